// Round 1
// baseline (8740.009 us; speedup 1.0000x reference)
//
#include <hip/hip_runtime.h>

#define D 128
#define EPSV 1e-5f

// ---------- one-time: Wt[l][i][o] = W[l][o][i] ----------
__global__ void wt_kernel(const float* __restrict__ W, float* __restrict__ Wt, int total) {
    int idx = blockIdx.x * blockDim.x + threadIdx.x;
    if (idx >= total) return;
    int l = idx / (D * D);
    int rem = idx - l * D * D;
    int o = rem / D;
    int i = rem - o * D;
    Wt[l * D * D + i * D + o] = W[idx];
}

// ---------- degree count over col (self-loop added in dis_kernel) ----------
__global__ void deg_kernel(const int* __restrict__ col, float* __restrict__ deg, int E) {
    int i = blockIdx.x * blockDim.x + threadIdx.x;
    int stride = gridDim.x * blockDim.x;
    for (; i < E; i += stride)
        unsafeAtomicAdd(&deg[col[i]], 1.0f);
}

__global__ void dis_kernel(float* __restrict__ deg, int N) {
    int i = blockIdx.x * blockDim.x + threadIdx.x;
    if (i < N) deg[i] = rsqrtf(deg[i] + 1.0f);   // +1 = self loop
}

// ---------- h' = dis[n] * (x @ W^T), 32 rows x 128 cols per block ----------
__global__ __launch_bounds__(256) void gemm_kernel(
    const float* __restrict__ x, const float* __restrict__ Wt,
    const float* __restrict__ dis, float* __restrict__ h, int N)
{
    __shared__ float xs[D * 36];                  // xs[j*36 + r] = x[n0+r][j]
    const int tid = threadIdx.x;
    const int o0 = (tid & 31) * 4;                // output col group
    const int r0 = (tid >> 5) * 4;                // row group

    for (int n0 = blockIdx.x * 32; n0 < N; n0 += gridDim.x * 32) {
        for (int idx = tid; idx < 32 * D; idx += 256) {
            int r = idx >> 7;
            int j = idx & 127;
            int n = n0 + r;
            xs[j * 36 + r] = (n < N) ? x[(long long)n * D + j] : 0.0f;
        }
        __syncthreads();

        float acc[4][4];
        #pragma unroll
        for (int a = 0; a < 4; a++)
            #pragma unroll
            for (int c = 0; c < 4; c++) acc[a][c] = 0.0f;

        #pragma unroll 8
        for (int j = 0; j < D; j++) {
            float4 wv = *reinterpret_cast<const float4*>(&Wt[j * D + o0]);   // L2-resident
            float4 xv = *reinterpret_cast<const float4*>(&xs[j * 36 + r0]);  // LDS broadcast
            float xa[4] = {xv.x, xv.y, xv.z, xv.w};
            float wa[4] = {wv.x, wv.y, wv.z, wv.w};
            #pragma unroll
            for (int a = 0; a < 4; a++)
                #pragma unroll
                for (int c = 0; c < 4; c++)
                    acc[a][c] += xa[a] * wa[c];
        }

        #pragma unroll
        for (int a = 0; a < 4; a++) {
            int n = n0 + r0 + a;
            if (n < N) {
                float d = dis[n];
                float4 o4 = make_float4(acc[a][0] * d, acc[a][1] * d,
                                        acc[a][2] * d, acc[a][3] * d);
                *reinterpret_cast<float4*>(&h[(long long)n * D + o0]) = o4;
            }
        }
        __syncthreads();
    }
}

// ---------- scatter: acc[col] += h'[row]  (norm folded into h' and finalize) ----------
__global__ __launch_bounds__(256) void scatter_kernel(
    const int* __restrict__ row, const int* __restrict__ col,
    const float* __restrict__ h, float* __restrict__ acc, int E)
{
    const int f4 = (threadIdx.x & 31) * 4;        // 32 lanes per edge, float4 each
    const int eslot = threadIdx.x >> 5;           // 8 edges per block iter
    long long e = (long long)blockIdx.x * 8 + eslot;
    const long long estride = (long long)gridDim.x * 8;
    for (; e < E; e += estride) {
        int r = row[e], c = col[e];
        float4 v = *reinterpret_cast<const float4*>(&h[(long long)r * D + f4]);
        float* dst = &acc[(long long)c * D + f4];
        unsafeAtomicAdd(dst + 0, v.x);
        unsafeAtomicAdd(dst + 1, v.y);
        unsafeAtomicAdd(dst + 2, v.z);
        unsafeAtomicAdd(dst + 3, v.w);
    }
}

// ---------- finalize aggregate: t = dis*(acc + h') + b; row-mean subtract; col stats ----------
__global__ __launch_bounds__(256) void epi1_kernel(
    const float* __restrict__ hbuf, float* __restrict__ t,   // t = acc, in place
    const float* __restrict__ dis, const float* __restrict__ bias,
    float* __restrict__ stats, int N)
{
    const int lane = threadIdx.x & 63;
    const int wid = threadIdx.x >> 6;             // 4 waves -> 4 rows per iter
    const int f0 = lane * 2;
    const float b0 = bias[f0], b1 = bias[f0 + 1];
    float s0 = 0, s1 = 0, q0 = 0, q1 = 0;

    for (int n = blockIdx.x * 4 + wid; n < N; n += gridDim.x * 4) {
        float d = dis[n];
        float2 a = *reinterpret_cast<const float2*>(&t[(long long)n * D + f0]);
        float2 hv = *reinterpret_cast<const float2*>(&hbuf[(long long)n * D + f0]);
        float t0 = d * (a.x + hv.x) + b0;         // self-loop: + dis*h'[n] = dis^2*h[n]
        float t1 = d * (a.y + hv.y) + b1;
        float m = t0 + t1;
        #pragma unroll
        for (int off = 1; off < 64; off <<= 1) m += __shfl_xor(m, off);
        m *= (1.0f / 128.0f);
        t0 -= m; t1 -= m;
        *reinterpret_cast<float2*>(&t[(long long)n * D + f0]) = make_float2(t0, t1);
        s0 += t0; s1 += t1;
        q0 += t0 * t0; q1 += t1 * t1;
    }

    __shared__ float red[4 * 256];
    red[wid * 256 + lane * 4 + 0] = s0;
    red[wid * 256 + lane * 4 + 1] = s1;
    red[wid * 256 + lane * 4 + 2] = q0;
    red[wid * 256 + lane * 4 + 3] = q1;
    __syncthreads();
    int tid = threadIdx.x;
    float v = red[tid] + red[256 + tid] + red[512 + tid] + red[768 + tid];
    int ln = tid >> 2, k = tid & 3;
    int f = ln * 2 + (k & 1);
    int off = (k >> 1) * D;                       // 0: sum, D: sumsq
    unsafeAtomicAdd(&stats[off + f], v);
}

// ---------- fold BN stats into scale/shift ----------
__global__ void stats_kernel(const float* __restrict__ stats,
                             const float* __restrict__ gamma,
                             const float* __restrict__ beta,
                             float* __restrict__ scsh, float Ninv)
{
    int j = threadIdx.x;
    float mu = stats[j] * Ninv;
    float var = stats[D + j] * Ninv - mu * mu;
    float inv = rsqrtf(var + EPSV);
    float sc = gamma[j] * inv;
    scsh[j] = sc;
    scsh[D + j] = beta[j] - mu * sc;
}

// ---------- apply BN: out = t*sc + sh ----------
__global__ __launch_bounds__(256) void epi2_kernel(
    const float* __restrict__ t, const float* __restrict__ scsh,
    float* __restrict__ out, long long total4)
{
    __shared__ float sc[D], sh[D];
    if (threadIdx.x < D) {
        sc[threadIdx.x] = scsh[threadIdx.x];
        sh[threadIdx.x] = scsh[D + threadIdx.x];
    }
    __syncthreads();
    long long i = (long long)blockIdx.x * blockDim.x + threadIdx.x;
    const long long stride = (long long)gridDim.x * blockDim.x;
    for (; i < total4; i += stride) {
        float4 v = reinterpret_cast<const float4*>(t)[i];
        int f0 = (int)((i * 4) & (D - 1));
        float4 o;
        o.x = v.x * sc[f0 + 0] + sh[f0 + 0];
        o.y = v.y * sc[f0 + 1] + sh[f0 + 1];
        o.z = v.z * sc[f0 + 2] + sh[f0 + 2];
        o.w = v.w * sc[f0 + 3] + sh[f0 + 3];
        reinterpret_cast<float4*>(out)[i] = o;
    }
}

extern "C" void kernel_launch(void* const* d_in, const int* in_sizes, int n_in,
                              void* d_out, int out_size, void* d_ws, size_t ws_size,
                              hipStream_t stream)
{
    const float* x_in  = (const float*)d_in[0];
    const int*   ei    = (const int*)d_in[1];     // int32 per harness contract
    const float* W     = (const float*)d_in[2];
    const float* bias  = (const float*)d_in[3];
    const float* gamma = (const float*)d_in[4];
    const float* beta  = (const float*)d_in[5];

    const int N = in_sizes[0] / D;
    const int E = in_sizes[1] / 2;
    const int L = in_sizes[2] / (D * D);
    const int* row = ei;                          // source
    const int* col = ei + E;                      // target

    // workspace layout (floats): xbuf | hbuf | acc | dis | stats | scsh | Wt
    float* ws    = (float*)d_ws;
    float* xbuf  = ws;
    float* hbuf  = xbuf + (size_t)N * D;
    float* acc   = hbuf + (size_t)N * D;
    float* dis   = acc + (size_t)N * D;
    float* stats = dis + N;
    float* scsh  = stats + 2 * D;
    float* Wt    = scsh + 2 * D;

    hipMemsetAsync(dis, 0, (size_t)N * sizeof(float), stream);
    deg_kernel<<<2048, 256, 0, stream>>>(col, dis, E);
    dis_kernel<<<(N + 255) / 256, 256, 0, stream>>>(dis, N);
    wt_kernel<<<(L * D * D + 255) / 256, 256, 0, stream>>>(W, Wt, L * D * D);

    const float Ninv = 1.0f / (float)N;
    const long long total4 = (long long)N * D / 4;

    const float* xcur = x_in;
    for (int l = 0; l < L; l++) {
        gemm_kernel<<<(N + 31) / 32, 256, 0, stream>>>(
            xcur, Wt + (size_t)l * D * D, dis, hbuf, N);
        hipMemsetAsync(acc, 0, (size_t)N * D * sizeof(float), stream);
        scatter_kernel<<<8192, 256, 0, stream>>>(row, col, hbuf, acc, E);
        hipMemsetAsync(stats, 0, 2 * D * sizeof(float), stream);
        epi1_kernel<<<4096, 256, 0, stream>>>(hbuf, acc, dis, bias + (size_t)l * D, stats, N);
        stats_kernel<<<1, D, 0, stream>>>(stats, gamma + (size_t)l * D, beta + (size_t)l * D, scsh, Ninv);
        float* xnext = (l == L - 1) ? (float*)d_out : xbuf;
        epi2_kernel<<<4096, 256, 0, stream>>>(acc, scsh, xnext, total4);
        xcur = xbuf;
    }
}

// Round 2
// 927.404 us; speedup vs baseline: 9.4242x; 9.4242x over previous
//
#include <hip/hip_runtime.h>

#define D 128
#define EPSV 1e-5f

// ---------- one-time: Wt[l][i][o] = W[l][o][i] ----------
__global__ void wt_kernel(const float* __restrict__ W, float* __restrict__ Wt, int total) {
    int idx = blockIdx.x * blockDim.x + threadIdx.x;
    if (idx >= total) return;
    int l = idx / (D * D);
    int rem = idx - l * D * D;
    int o = rem / D;
    int i = rem - o * D;
    Wt[l * D * D + i * D + o] = W[idx];
}

// ---------- degree count (int) over col ----------
__global__ void count_kernel(const int* __restrict__ col, int* __restrict__ cnt, int E) {
    int i = blockIdx.x * blockDim.x + threadIdx.x;
    int stride = gridDim.x * blockDim.x;
    for (; i < E; i += stride)
        atomicAdd(&cnt[col[i]], 1);
}

__global__ void dis_kernel(const int* __restrict__ cnt, float* __restrict__ dis, int N) {
    int i = blockIdx.x * blockDim.x + threadIdx.x;
    if (i < N) dis[i] = rsqrtf((float)cnt[i] + 1.0f);   // +1 = self loop
}

// ---------- exclusive scan of cnt -> offs (3-kernel block scan) ----------
__global__ void scan1_kernel(const int* __restrict__ cnt, int* __restrict__ offs,
                             int* __restrict__ bsum, int N) {
    __shared__ int s[256];
    int tid = threadIdx.x;
    int i = blockIdx.x * 256 + tid;
    int v = (i < N) ? cnt[i] : 0;
    s[tid] = v;
    __syncthreads();
    for (int off = 1; off < 256; off <<= 1) {
        int t = (tid >= off) ? s[tid - off] : 0;
        __syncthreads();
        s[tid] += t;
        __syncthreads();
    }
    if (i < N) offs[i] = s[tid] - v;          // exclusive within block
    if (tid == 255) bsum[blockIdx.x] = s[255];
}

__global__ void scan2_kernel(int* __restrict__ bsum, int NB) {
    __shared__ int s[512];
    int tid = threadIdx.x;
    int v = (tid < NB) ? bsum[tid] : 0;
    s[tid] = v;
    __syncthreads();
    for (int off = 1; off < 512; off <<= 1) {
        int t = (tid >= off) ? s[tid - off] : 0;
        __syncthreads();
        s[tid] += t;
        __syncthreads();
    }
    if (tid < NB) bsum[tid] = s[tid] - v;     // exclusive block prefix
}

__global__ void scan3_kernel(int* __restrict__ offs, const int* __restrict__ bsum,
                             int* __restrict__ cursor, int N, int E) {
    int i = blockIdx.x * 256 + threadIdx.x;
    if (i < N) {
        int o = offs[i] + bsum[blockIdx.x];
        offs[i] = o;
        cursor[i] = o;
    }
    if (i == 0) offs[N] = E;
}

// ---------- fill CSR: srcs[slot(col)] = row ----------
__global__ void fill_kernel(const int* __restrict__ row, const int* __restrict__ col,
                            int* __restrict__ cursor, int* __restrict__ srcs, int E) {
    int i = blockIdx.x * blockDim.x + threadIdx.x;
    int stride = gridDim.x * blockDim.x;
    for (; i < E; i += stride) {
        int pos = atomicAdd(&cursor[col[i]], 1);
        srcs[pos] = row[i];
    }
}

// ---------- h' = dis[n] * (x @ W^T), 32 rows x 128 cols per block ----------
__global__ __launch_bounds__(256) void gemm_kernel(
    const float* __restrict__ x, const float* __restrict__ Wt,
    const float* __restrict__ dis, float* __restrict__ h, int N)
{
    __shared__ float xs[D * 36];
    const int tid = threadIdx.x;
    const int o0 = (tid & 31) * 4;
    const int r0 = (tid >> 5) * 4;

    for (int n0 = blockIdx.x * 32; n0 < N; n0 += gridDim.x * 32) {
        for (int idx = tid; idx < 32 * D; idx += 256) {
            int r = idx >> 7;
            int j = idx & 127;
            int n = n0 + r;
            xs[j * 36 + r] = (n < N) ? x[(long long)n * D + j] : 0.0f;
        }
        __syncthreads();

        float acc[4][4];
        #pragma unroll
        for (int a = 0; a < 4; a++)
            #pragma unroll
            for (int c = 0; c < 4; c++) acc[a][c] = 0.0f;

        #pragma unroll 8
        for (int j = 0; j < D; j++) {
            float4 wv = *reinterpret_cast<const float4*>(&Wt[j * D + o0]);
            float4 xv = *reinterpret_cast<const float4*>(&xs[j * 36 + r0]);
            float xa[4] = {xv.x, xv.y, xv.z, xv.w};
            float wa[4] = {wv.x, wv.y, wv.z, wv.w};
            #pragma unroll
            for (int a = 0; a < 4; a++)
                #pragma unroll
                for (int c = 0; c < 4; c++)
                    acc[a][c] += xa[a] * wa[c];
        }

        #pragma unroll
        for (int a = 0; a < 4; a++) {
            int n = n0 + r0 + a;
            if (n < N) {
                float d = dis[n];
                float4 o4 = make_float4(acc[a][0] * d, acc[a][1] * d,
                                        acc[a][2] * d, acc[a][3] * d);
                *reinterpret_cast<float4*>(&h[(long long)n * D + o0]) = o4;
            }
        }
        __syncthreads();
    }
}

// ---------- fused gather + finalize: t = dis*(h'[c] + sum_neigh h'[r]) + b,
//            row-mean subtract, col stats ----------
__global__ __launch_bounds__(256) void gather_kernel(
    const float* __restrict__ h, const int* __restrict__ offs,
    const int* __restrict__ srcs, const float* __restrict__ dis,
    const float* __restrict__ bias, float* __restrict__ t,
    float* __restrict__ stats, int N)
{
    const int tid = threadIdx.x;
    const int lane32 = tid & 31;
    const int grp = tid >> 5;                  // 8 node-groups per block
    const int f4 = lane32 * 4;
    const float4 bv = *reinterpret_cast<const float4*>(&bias[f4]);
    float ssum[4] = {0, 0, 0, 0}, ssq[4] = {0, 0, 0, 0};

    for (int c = blockIdx.x * 8 + grp; c < N; c += gridDim.x * 8) {
        float4 a = *reinterpret_cast<const float4*>(&h[(long long)c * D + f4]);  // self
        const int k0 = offs[c], k1 = offs[c + 1];
        for (int kb = k0; kb < k1; kb += 32) {
            int kk = kb + lane32;
            int rl = (kk < k1) ? srcs[kk] : 0;   // neighbor ids in registers
            int cnt = min(32, k1 - kb);
            for (int j = 0; j < cnt; j++) {
                int r = __shfl(rl, j, 32);
                float4 v = *reinterpret_cast<const float4*>(&h[(long long)r * D + f4]);
                a.x += v.x; a.y += v.y; a.z += v.z; a.w += v.w;
            }
        }
        float d = dis[c];
        float t0 = d * a.x + bv.x;
        float t1 = d * a.y + bv.y;
        float t2 = d * a.z + bv.z;
        float t3 = d * a.w + bv.w;
        float s = t0 + t1 + t2 + t3;
        #pragma unroll
        for (int off = 1; off < 32; off <<= 1) s += __shfl_xor(s, off, 32);
        float m = s * (1.0f / 128.0f);
        t0 -= m; t1 -= m; t2 -= m; t3 -= m;
        *reinterpret_cast<float4*>(&t[(long long)c * D + f4]) =
            make_float4(t0, t1, t2, t3);
        ssum[0] += t0; ssum[1] += t1; ssum[2] += t2; ssum[3] += t3;
        ssq[0] += t0 * t0; ssq[1] += t1 * t1; ssq[2] += t2 * t2; ssq[3] += t3 * t3;
    }

    __shared__ float red[256 * 8];
    #pragma unroll
    for (int j = 0; j < 4; j++) {
        red[tid * 8 + j] = ssum[j];
        red[tid * 8 + 4 + j] = ssq[j];
    }
    __syncthreads();
    // thread o handles stats[o]: o<128 -> sum of feature o; else sumsq of o-128
    int o = tid;
    int f = o & 127;
    int sq = (o >> 7) & 1;
    int j = f & 3;
    int l32 = f >> 2;
    float v = 0;
    #pragma unroll
    for (int g = 0; g < 8; g++)
        v += red[(g * 32 + l32) * 8 + sq * 4 + j];
    unsafeAtomicAdd(&stats[o], v);
}

// ---------- fold BN stats into scale/shift ----------
__global__ void stats_kernel(const float* __restrict__ stats,
                             const float* __restrict__ gamma,
                             const float* __restrict__ beta,
                             float* __restrict__ scsh, float Ninv)
{
    int j = threadIdx.x;
    float mu = stats[j] * Ninv;
    float var = stats[D + j] * Ninv - mu * mu;
    float inv = rsqrtf(var + EPSV);
    float sc = gamma[j] * inv;
    scsh[j] = sc;
    scsh[D + j] = beta[j] - mu * sc;
}

// ---------- apply BN (in place or to out): y = t*sc + sh ----------
__global__ __launch_bounds__(256) void epi2_kernel(
    const float* __restrict__ t, const float* __restrict__ scsh,
    float* __restrict__ out, long long total4)
{
    __shared__ float sc[D], sh[D];
    if (threadIdx.x < D) {
        sc[threadIdx.x] = scsh[threadIdx.x];
        sh[threadIdx.x] = scsh[D + threadIdx.x];
    }
    __syncthreads();
    long long i = (long long)blockIdx.x * blockDim.x + threadIdx.x;
    const long long stride = (long long)gridDim.x * blockDim.x;
    for (; i < total4; i += stride) {
        float4 v = reinterpret_cast<const float4*>(t)[i];
        int f0 = (int)((i * 4) & (D - 1));
        float4 o;
        o.x = v.x * sc[f0 + 0] + sh[f0 + 0];
        o.y = v.y * sc[f0 + 1] + sh[f0 + 1];
        o.z = v.z * sc[f0 + 2] + sh[f0 + 2];
        o.w = v.w * sc[f0 + 3] + sh[f0 + 3];
        reinterpret_cast<float4*>(out)[i] = o;
    }
}

extern "C" void kernel_launch(void* const* d_in, const int* in_sizes, int n_in,
                              void* d_out, int out_size, void* d_ws, size_t ws_size,
                              hipStream_t stream)
{
    const float* x_in  = (const float*)d_in[0];
    const int*   ei    = (const int*)d_in[1];
    const float* W     = (const float*)d_in[2];
    const float* bias  = (const float*)d_in[3];
    const float* gamma = (const float*)d_in[4];
    const float* beta  = (const float*)d_in[5];

    const int N = in_sizes[0] / D;
    const int E = in_sizes[1] / 2;
    const int L = in_sizes[2] / (D * D);
    const int* row = ei;           // source
    const int* col = ei + E;       // target
    const int NB = (N + 255) / 256;

    // workspace layout: hbuf | tbuf | dis | stats | scsh | Wt || cnt | offs | cursor | srcs | bsum
    float* ws    = (float*)d_ws;
    float* hbuf  = ws;
    float* tbuf  = hbuf + (size_t)N * D;
    float* dis   = tbuf + (size_t)N * D;
    float* stats = dis + N;
    float* scsh  = stats + 2 * D;
    float* Wt    = scsh + 2 * D;
    int*   cnt    = (int*)(Wt + (size_t)L * D * D);
    int*   offs   = cnt + N;
    int*   cursor = offs + (N + 1);
    int*   srcs   = cursor + N;
    int*   bsum   = srcs + E;

    hipMemsetAsync(cnt, 0, (size_t)N * sizeof(int), stream);
    count_kernel<<<2048, 256, 0, stream>>>(col, cnt, E);
    dis_kernel<<<NB, 256, 0, stream>>>(cnt, dis, N);
    wt_kernel<<<(L * D * D + 255) / 256, 256, 0, stream>>>(W, Wt, L * D * D);
    scan1_kernel<<<NB, 256, 0, stream>>>(cnt, offs, bsum, N);
    scan2_kernel<<<1, 512, 0, stream>>>(bsum, NB);
    scan3_kernel<<<NB, 256, 0, stream>>>(offs, bsum, cursor, N, E);
    fill_kernel<<<2048, 256, 0, stream>>>(row, col, cursor, srcs, E);

    const float Ninv = 1.0f / (float)N;
    const long long total4 = (long long)N * D / 4;

    const float* xcur = x_in;
    for (int l = 0; l < L; l++) {
        gemm_kernel<<<(N + 31) / 32, 256, 0, stream>>>(
            xcur, Wt + (size_t)l * D * D, dis, hbuf, N);
        hipMemsetAsync(stats, 0, 2 * D * sizeof(float), stream);
        gather_kernel<<<2048, 256, 0, stream>>>(
            hbuf, offs, srcs, dis, bias + (size_t)l * D, tbuf, stats, N);
        stats_kernel<<<1, D, 0, stream>>>(
            stats, gamma + (size_t)l * D, beta + (size_t)l * D, scsh, Ninv);
        float* xnext = (l == L - 1) ? (float*)d_out : tbuf;   // epi2 in place
        epi2_kernel<<<4096, 256, 0, stream>>>(tbuf, scsh, xnext, total4);
        xcur = tbuf;
    }
}

// Round 3
// 650.167 us; speedup vs baseline: 13.4427x; 1.4264x over previous
//
#include <hip/hip_runtime.h>

#define D 128
#define EPSV 1e-5f

typedef _Float16 f16;
typedef __attribute__((ext_vector_type(8))) _Float16 f16x8;
typedef __attribute__((ext_vector_type(4))) _Float16 f16x4;
typedef __attribute__((ext_vector_type(4))) float f32x4;

// ---------- x f32 -> fp16 ----------
__global__ __launch_bounds__(256) void cvt_kernel(const float* __restrict__ x,
                                                  f16* __restrict__ xh, long long total4) {
    long long i = (long long)blockIdx.x * blockDim.x + threadIdx.x;
    const long long stride = (long long)gridDim.x * blockDim.x;
    for (; i < total4; i += stride) {
        float4 v = reinterpret_cast<const float4*>(x)[i];
        f16x4 o;
        o[0] = (f16)v.x; o[1] = (f16)v.y; o[2] = (f16)v.z; o[3] = (f16)v.w;
        reinterpret_cast<f16x4*>(xh)[i] = o;
    }
}

// ---------- fold BN of prev layer into W: Wfo[o][k] = fp16(W[o][k]*sc[k]),
//            shW[o] = sum_k sh[k]*W[o][k] ----------
__global__ void fold_kernel(const float* __restrict__ W, const float* __restrict__ scsh,
                            int use_id, f16* __restrict__ Wfo, float* __restrict__ shW) {
    const int o = blockIdx.x;          // 128 blocks
    const int k = threadIdx.x;         // 128 threads
    float w = W[o * D + k];
    float sc = use_id ? 1.0f : scsh[k];
    float sh = use_id ? 0.0f : scsh[D + k];
    Wfo[o * D + k] = (f16)(w * sc);
    float v = sh * w;
    #pragma unroll
    for (int off = 1; off < 64; off <<= 1) v += __shfl_xor(v, off, 64);
    __shared__ float red[2];
    if ((k & 63) == 0) red[k >> 6] = v;
    __syncthreads();
    if (k == 0) shW[o] = red[0] + red[1];
}

// ---------- degree count (int) over col ----------
__global__ void count_kernel(const int* __restrict__ col, int* __restrict__ cnt, int E) {
    int i = blockIdx.x * blockDim.x + threadIdx.x;
    int stride = gridDim.x * blockDim.x;
    for (; i < E; i += stride)
        atomicAdd(&cnt[col[i]], 1);
}

__global__ void dis_kernel(const int* __restrict__ cnt, float* __restrict__ dis, int N) {
    int i = blockIdx.x * blockDim.x + threadIdx.x;
    if (i < N) dis[i] = rsqrtf((float)cnt[i] + 1.0f);   // +1 = self loop
}

// ---------- exclusive scan of cnt -> offs ----------
__global__ void scan1_kernel(const int* __restrict__ cnt, int* __restrict__ offs,
                             int* __restrict__ bsum, int N) {
    __shared__ int s[256];
    int tid = threadIdx.x;
    int i = blockIdx.x * 256 + tid;
    int v = (i < N) ? cnt[i] : 0;
    s[tid] = v;
    __syncthreads();
    for (int off = 1; off < 256; off <<= 1) {
        int t = (tid >= off) ? s[tid - off] : 0;
        __syncthreads();
        s[tid] += t;
        __syncthreads();
    }
    if (i < N) offs[i] = s[tid] - v;
    if (tid == 255) bsum[blockIdx.x] = s[255];
}

__global__ void scan2_kernel(int* __restrict__ bsum, int NB) {
    __shared__ int s[512];
    int tid = threadIdx.x;
    int v = (tid < NB) ? bsum[tid] : 0;
    s[tid] = v;
    __syncthreads();
    for (int off = 1; off < 512; off <<= 1) {
        int t = (tid >= off) ? s[tid - off] : 0;
        __syncthreads();
        s[tid] += t;
        __syncthreads();
    }
    if (tid < NB) bsum[tid] = s[tid] - v;
}

__global__ void scan3_kernel(int* __restrict__ offs, const int* __restrict__ bsum,
                             int* __restrict__ cursor, int N, int E) {
    int i = blockIdx.x * 256 + threadIdx.x;
    if (i < N) {
        int o = offs[i] + bsum[blockIdx.x];
        offs[i] = o;
        cursor[i] = o;
    }
    if (i == 0) offs[N] = E;
}

__global__ void fill_kernel(const int* __restrict__ row, const int* __restrict__ col,
                            int* __restrict__ cursor, int* __restrict__ srcs, int E) {
    int i = blockIdx.x * blockDim.x + threadIdx.x;
    int stride = gridDim.x * blockDim.x;
    for (; i < E; i += stride) {
        int pos = atomicAdd(&cursor[col[i]], 1);
        srcs[pos] = row[i];
    }
}

// ---------- MFMA GEMM: h[n][o] = fp16( dis[n]*( sum_k xh[n][k]*Wfo[o][k] + shW[o] ) )
// A = W fragments (regs), B = x-row fragments; v_mfma_f32_16x16x32_f16
// A[m][k]: m = lane&15 (=o_local), k = kb*32 + (lane>>4)*8 + j
// B[k][n]: n = lane&15 (=row_local), k same
// D[m][n]: n = lane&15 (=row_local), m = (lane>>4)*4 + reg (=o_local)
__global__ __launch_bounds__(256) void gemm_kernel(
    const f16* __restrict__ xh, const f16* __restrict__ Wfo,
    const float* __restrict__ shW, const float* __restrict__ dis,
    f16* __restrict__ h, int N, int nrg)
{
    const int lane = threadIdx.x & 63;
    const int l15 = lane & 15;
    const int lh = lane >> 4;            // 0..3

    // W fragments: 8 o-tiles x 4 k-blocks, held in registers
    f16x8 af[8][4];
    #pragma unroll
    for (int t = 0; t < 8; t++)
        #pragma unroll
        for (int kb = 0; kb < 4; kb++)
            af[t][kb] = *reinterpret_cast<const f16x8*>(
                &Wfo[(t * 16 + l15) * D + kb * 32 + lh * 8]);

    const int wid = (blockIdx.x * blockDim.x + threadIdx.x) >> 6;
    const int nwaves = (gridDim.x * blockDim.x) >> 6;

    for (int rg = wid; rg < nrg; rg += nwaves) {
        int row = rg * 16 + l15;
        int rrow = min(row, N - 1);
        f16x8 bf[4];
        #pragma unroll
        for (int kb = 0; kb < 4; kb++)
            bf[kb] = *reinterpret_cast<const f16x8*>(
                &xh[(long long)rrow * D + kb * 32 + lh * 8]);
        float d = dis[rrow];
        bool ok = (row < N);

        #pragma unroll
        for (int t = 0; t < 8; t++) {
            f32x4 acc = {0.0f, 0.0f, 0.0f, 0.0f};
            #pragma unroll
            for (int kb = 0; kb < 4; kb++)
                acc = __builtin_amdgcn_mfma_f32_16x16x32_f16(af[t][kb], bf[kb], acc, 0, 0, 0);
            int o0 = t * 16 + lh * 4;
            float4 sw = *reinterpret_cast<const float4*>(&shW[o0]);
            f16x4 ov;
            ov[0] = (f16)(d * (acc[0] + sw.x));
            ov[1] = (f16)(d * (acc[1] + sw.y));
            ov[2] = (f16)(d * (acc[2] + sw.z));
            ov[3] = (f16)(d * (acc[3] + sw.w));
            if (ok)
                *reinterpret_cast<f16x4*>(&h[(long long)row * D + o0]) = ov;
        }
    }
}

// ---------- fused gather + finalize (fp16 h, fp16 t, f32 stats) ----------
__global__ __launch_bounds__(256) void gather_kernel(
    const f16* __restrict__ h, const int* __restrict__ offs,
    const int* __restrict__ srcs, const float* __restrict__ dis,
    const float* __restrict__ bias, f16* __restrict__ t,
    float* __restrict__ stats, int N)
{
    const int tid = threadIdx.x;
    const int lane32 = tid & 31;
    const int grp = tid >> 5;
    const int f4 = lane32 * 4;
    const float4 bv = *reinterpret_cast<const float4*>(&bias[f4]);
    float ssum[4] = {0, 0, 0, 0}, ssq[4] = {0, 0, 0, 0};

    for (int c = blockIdx.x * 8 + grp; c < N; c += gridDim.x * 8) {
        f16x4 hv = *reinterpret_cast<const f16x4*>(&h[(long long)c * D + f4]);  // self
        float a0 = (float)hv[0], a1 = (float)hv[1], a2 = (float)hv[2], a3 = (float)hv[3];
        const int k0 = offs[c], k1 = offs[c + 1];
        for (int kb = k0; kb < k1; kb += 32) {
            int kk = kb + lane32;
            int rl = (kk < k1) ? srcs[kk] : 0;
            int cntn = min(32, k1 - kb);
            for (int j = 0; j < cntn; j++) {
                int r = __shfl(rl, j, 32);
                f16x4 v = *reinterpret_cast<const f16x4*>(&h[(long long)r * D + f4]);
                a0 += (float)v[0]; a1 += (float)v[1];
                a2 += (float)v[2]; a3 += (float)v[3];
            }
        }
        float d = dis[c];
        float t0 = d * a0 + bv.x;
        float t1 = d * a1 + bv.y;
        float t2 = d * a2 + bv.z;
        float t3 = d * a3 + bv.w;
        float s = t0 + t1 + t2 + t3;
        #pragma unroll
        for (int off = 1; off < 32; off <<= 1) s += __shfl_xor(s, off, 32);
        float m = s * (1.0f / 128.0f);
        t0 -= m; t1 -= m; t2 -= m; t3 -= m;
        f16x4 ov;
        ov[0] = (f16)t0; ov[1] = (f16)t1; ov[2] = (f16)t2; ov[3] = (f16)t3;
        *reinterpret_cast<f16x4*>(&t[(long long)c * D + f4]) = ov;
        ssum[0] += t0; ssum[1] += t1; ssum[2] += t2; ssum[3] += t3;
        ssq[0] += t0 * t0; ssq[1] += t1 * t1; ssq[2] += t2 * t2; ssq[3] += t3 * t3;
    }

    __shared__ float red[256 * 8];
    #pragma unroll
    for (int j = 0; j < 4; j++) {
        red[tid * 8 + j] = ssum[j];
        red[tid * 8 + 4 + j] = ssq[j];
    }
    __syncthreads();
    int o = tid;
    int f = o & 127;
    int sq = (o >> 7) & 1;
    int j = f & 3;
    int l32 = f >> 2;
    float v = 0;
    #pragma unroll
    for (int g = 0; g < 8; g++)
        v += red[(g * 32 + l32) * 8 + sq * 4 + j];
    unsafeAtomicAdd(&stats[o], v);
}

// ---------- fold BN stats into scale/shift ----------
__global__ void stats_kernel(const float* __restrict__ stats,
                             const float* __restrict__ gamma,
                             const float* __restrict__ beta,
                             float* __restrict__ scsh, float Ninv)
{
    int j = threadIdx.x;
    float mu = stats[j] * Ninv;
    float var = stats[D + j] * Ninv - mu * mu;
    float inv = rsqrtf(var + EPSV);
    float sc = gamma[j] * inv;
    scsh[j] = sc;
    scsh[D + j] = beta[j] - mu * sc;
}

// ---------- final BN apply: out(f32) = t(fp16)*sc + sh ----------
__global__ __launch_bounds__(256) void epi2_kernel(
    const f16* __restrict__ t, const float* __restrict__ scsh,
    float* __restrict__ out, long long total4)
{
    __shared__ float sc[D], sh[D];
    if (threadIdx.x < D) {
        sc[threadIdx.x] = scsh[threadIdx.x];
        sh[threadIdx.x] = scsh[D + threadIdx.x];
    }
    __syncthreads();
    long long i = (long long)blockIdx.x * blockDim.x + threadIdx.x;
    const long long stride = (long long)gridDim.x * blockDim.x;
    for (; i < total4; i += stride) {
        f16x4 v = reinterpret_cast<const f16x4*>(t)[i];
        int f0 = (int)((i * 4) & (D - 1));
        float4 o;
        o.x = (float)v[0] * sc[f0 + 0] + sh[f0 + 0];
        o.y = (float)v[1] * sc[f0 + 1] + sh[f0 + 1];
        o.z = (float)v[2] * sc[f0 + 2] + sh[f0 + 2];
        o.w = (float)v[3] * sc[f0 + 3] + sh[f0 + 3];
        reinterpret_cast<float4*>(out)[i] = o;
    }
}

extern "C" void kernel_launch(void* const* d_in, const int* in_sizes, int n_in,
                              void* d_out, int out_size, void* d_ws, size_t ws_size,
                              hipStream_t stream)
{
    const float* x_in  = (const float*)d_in[0];
    const int*   ei    = (const int*)d_in[1];
    const float* W     = (const float*)d_in[2];
    const float* bias  = (const float*)d_in[3];
    const float* gamma = (const float*)d_in[4];
    const float* beta  = (const float*)d_in[5];

    const int N = in_sizes[0] / D;
    const int E = in_sizes[1] / 2;
    const int L = in_sizes[2] / (D * D);
    const int* row = ei;           // source
    const int* col = ei + E;       // target
    const int NB = (N + 255) / 256;
    const int nrg = (N + 15) / 16;

    // ws layout: [f16: xh | hbuf | tbuf | Wfo] [f32: dis | stats | scsh | shW] [int: cnt | offs | cursor | srcs | bsum]
    f16* xh   = (f16*)d_ws;
    f16* hbuf = xh + (size_t)N * D;
    f16* tbuf = hbuf + (size_t)N * D;
    f16* Wfo  = tbuf + (size_t)N * D;
    float* dis   = (float*)(Wfo + D * D);
    float* stats = dis + N;
    float* scsh  = stats + 2 * D;
    float* shW   = scsh + 2 * D;
    int* cnt    = (int*)(shW + D);
    int* offs   = cnt + N;
    int* cursor = offs + (N + 1);
    int* srcs   = cursor + N;
    int* bsum   = srcs + E;

    hipMemsetAsync(cnt, 0, (size_t)N * sizeof(int), stream);
    count_kernel<<<2048, 256, 0, stream>>>(col, cnt, E);
    dis_kernel<<<NB, 256, 0, stream>>>(cnt, dis, N);
    scan1_kernel<<<NB, 256, 0, stream>>>(cnt, offs, bsum, N);
    scan2_kernel<<<1, 512, 0, stream>>>(bsum, NB);
    scan3_kernel<<<NB, 256, 0, stream>>>(offs, bsum, cursor, N, E);
    fill_kernel<<<2048, 256, 0, stream>>>(row, col, cursor, srcs, E);

    const float Ninv = 1.0f / (float)N;
    const long long total4 = (long long)N * D / 4;

    cvt_kernel<<<2048, 256, 0, stream>>>(x_in, xh, total4);
    fold_kernel<<<D, D, 0, stream>>>(W, scsh, 1, Wfo, shW);   // layer 0: identity fold

    const f16* xcur = xh;
    for (int l = 0; l < L; l++) {
        gemm_kernel<<<512, 256, 0, stream>>>(xcur, Wfo, shW, dis, hbuf, N, nrg);
        hipMemsetAsync(stats, 0, 2 * D * sizeof(float), stream);
        gather_kernel<<<2048, 256, 0, stream>>>(
            hbuf, offs, srcs, dis, bias + (size_t)l * D, tbuf, stats, N);
        stats_kernel<<<1, D, 0, stream>>>(
            stats, gamma + (size_t)l * D, beta + (size_t)l * D, scsh, Ninv);
        if (l < L - 1)
            fold_kernel<<<D, D, 0, stream>>>(W + (size_t)(l + 1) * D * D, scsh, 0, Wfo, shW);
        else
            epi2_kernel<<<4096, 256, 0, stream>>>(tbuf, scsh, (float*)d_out, total4);
        xcur = tbuf;
    }
}

// Round 4
// 527.645 us; speedup vs baseline: 16.5642x; 1.2322x over previous
//
#include <hip/hip_runtime.h>

#define D 128
#define EPSV 1e-5f

typedef _Float16 f16;
typedef __attribute__((ext_vector_type(8))) _Float16 f16x8;
typedef __attribute__((ext_vector_type(4))) _Float16 f16x4;
typedef __attribute__((ext_vector_type(4))) float f32x4;

// ---------- x f32 -> fp16 ----------
__global__ __launch_bounds__(256) void cvt_kernel(const float* __restrict__ x,
                                                  f16* __restrict__ xh, long long total4) {
    long long i = (long long)blockIdx.x * blockDim.x + threadIdx.x;
    const long long stride = (long long)gridDim.x * blockDim.x;
    for (; i < total4; i += stride) {
        float4 v = reinterpret_cast<const float4*>(x)[i];
        f16x4 o;
        o[0] = (f16)v.x; o[1] = (f16)v.y; o[2] = (f16)v.z; o[3] = (f16)v.w;
        reinterpret_cast<f16x4*>(xh)[i] = o;
    }
}

// ---------- fold BN of prev layer into W ----------
__global__ void fold_kernel(const float* __restrict__ W, const float* __restrict__ scsh,
                            int use_id, f16* __restrict__ Wfo, float* __restrict__ shW) {
    const int o = blockIdx.x;
    const int k = threadIdx.x;
    float w = W[o * D + k];
    float sc = use_id ? 1.0f : scsh[k];
    float sh = use_id ? 0.0f : scsh[D + k];
    Wfo[o * D + k] = (f16)(w * sc);
    float v = sh * w;
    #pragma unroll
    for (int off = 1; off < 64; off <<= 1) v += __shfl_xor(v, off, 64);
    __shared__ float red[2];
    if ((k & 63) == 0) red[k >> 6] = v;
    __syncthreads();
    if (k == 0) shW[o] = red[0] + red[1];
}

// ================= bucketized CSR build =================
// bucket b = col >> 8 (256 cols/bucket), part p = (edge_chunk)&7.
// Segment (b,p) keeps writes XCD-local-ish and line-sequential.

// ---- A1: per-(bucket,part) histogram, LDS-privatized ----
__global__ __launch_bounds__(256) void bcount_kernel(const int* __restrict__ col,
                                                     int* __restrict__ gb, int E, int seg) {
    __shared__ int s[4096];
    for (int j = threadIdx.x; j < seg; j += 256) s[j] = 0;
    __syncthreads();
    int i = blockIdx.x * 256 + threadIdx.x;
    const int stride = gridDim.x * 256;
    for (; i < E; i += stride) {
        int b = col[i] >> 8;
        int p = (i >> 8) & 7;
        atomicAdd(&s[b * 8 + p], 1);
    }
    __syncthreads();
    for (int j = threadIdx.x; j < seg; j += 256)
        if (s[j]) atomicAdd(&gb[j], s[j]);
}

// ---- A2: exclusive scan of 4096 segment counts (1 block, 1024 thr) ----
__global__ __launch_bounds__(1024) void bscan_kernel(const int* __restrict__ gb,
                                                     int* __restrict__ soff,
                                                     int* __restrict__ cur) {
    __shared__ int s[1024];
    const int tid = threadIdx.x;
    const int base = tid * 4;
    int g0 = gb[base], g1 = gb[base + 1], g2 = gb[base + 2], g3 = gb[base + 3];
    int my = g0 + g1 + g2 + g3;
    s[tid] = my;
    __syncthreads();
    for (int off = 1; off < 1024; off <<= 1) {
        int t = (tid >= off) ? s[tid - off] : 0;
        __syncthreads();
        s[tid] += t;
        __syncthreads();
    }
    int ex = s[tid] - my;
    soff[base] = ex;           cur[(base + 0) * 16] = ex;  ex += g0;
    soff[base + 1] = ex;       cur[(base + 1) * 16] = ex;  ex += g1;
    soff[base + 2] = ex;       cur[(base + 2) * 16] = ex;  ex += g2;
    soff[base + 3] = ex;       cur[(base + 3) * 16] = ex;
    if (tid == 1023) soff[4096] = s[1023];
}

// ---- A3: scatter (row,col) pairs into segments ----
__global__ __launch_bounds__(256) void bfill_kernel(const int* __restrict__ row,
                                                    const int* __restrict__ col,
                                                    int* __restrict__ cur,
                                                    int2* __restrict__ bpairs, int E) {
    const int p = blockIdx.x & 7;
    int i = blockIdx.x * 256 + threadIdx.x;
    const int stride = gridDim.x * 256;   // gridDim %8==0 keeps p == (i>>8)&7
    for (; i < E; i += stride) {
        int c = col[i];
        int b = c >> 8;
        int pos = atomicAdd(&cur[(b * 8 + p) * 16], 1);
        bpairs[pos] = make_int2(row[i], c);
    }
}

// ---- B: per-bucket degree count + dis ----
__global__ __launch_bounds__(256) void bdeg_kernel(const int2* __restrict__ bpairs,
                                                   const int* __restrict__ soff,
                                                   int* __restrict__ deg,
                                                   float* __restrict__ dis, int N) {
    __shared__ int dc[256];
    const int b = blockIdx.x;
    const int tid = threadIdx.x;
    dc[tid] = 0;
    __syncthreads();
    const int s0 = soff[b * 8], s1 = soff[(b + 1) * 8];
    for (int k = s0 + tid; k < s1; k += 256)
        atomicAdd(&dc[bpairs[k].y & 255], 1);
    __syncthreads();
    int c = (b << 8) + tid;
    if (c < N) {
        int dv = dc[tid];
        deg[c] = dv;
        dis[c] = rsqrtf((float)dv + 1.0f);   // +1 = self loop
    }
}

// ---- exclusive scan of deg -> offs ----
__global__ void scan1_kernel(const int* __restrict__ cnt, int* __restrict__ offs,
                             int* __restrict__ bsum, int N) {
    __shared__ int s[256];
    int tid = threadIdx.x;
    int i = blockIdx.x * 256 + tid;
    int v = (i < N) ? cnt[i] : 0;
    s[tid] = v;
    __syncthreads();
    for (int off = 1; off < 256; off <<= 1) {
        int t = (tid >= off) ? s[tid - off] : 0;
        __syncthreads();
        s[tid] += t;
        __syncthreads();
    }
    if (i < N) offs[i] = s[tid] - v;
    if (tid == 255) bsum[blockIdx.x] = s[255];
}

__global__ void scan2_kernel(int* __restrict__ bsum, int NB) {
    __shared__ int s[512];
    int tid = threadIdx.x;
    int v = (tid < NB) ? bsum[tid] : 0;
    s[tid] = v;
    __syncthreads();
    for (int off = 1; off < 512; off <<= 1) {
        int t = (tid >= off) ? s[tid - off] : 0;
        __syncthreads();
        s[tid] += t;
        __syncthreads();
    }
    if (tid < NB) bsum[tid] = s[tid] - v;
}

__global__ void scan3_kernel(int* __restrict__ offs, const int* __restrict__ bsum,
                             int N, int E) {
    int i = blockIdx.x * 256 + threadIdx.x;
    if (i < N) offs[i] += bsum[blockIdx.x];
    if (i == 0) offs[N] = E;
}

// ---- C: per-bucket fill of srcs (writes localized to bucket CSR range) ----
__global__ __launch_bounds__(256) void cfill_kernel(const int2* __restrict__ bpairs,
                                                    const int* __restrict__ soff,
                                                    const int* __restrict__ offs,
                                                    int* __restrict__ srcs, int N) {
    __shared__ int lc[256];
    const int b = blockIdx.x;
    const int tid = threadIdx.x;
    int c = (b << 8) + tid;
    lc[tid] = (c < N) ? offs[c] : 0;
    __syncthreads();
    const int s0 = soff[b * 8], s1 = soff[(b + 1) * 8];
    for (int k = s0 + tid; k < s1; k += 256) {
        int2 pr = bpairs[k];
        int pos = atomicAdd(&lc[pr.y & 255], 1);
        srcs[pos] = pr.x;
    }
}

// ================= per-layer kernels =================

// ---- MFMA GEMM: h[n][o] = fp16( dis[n]*( sum_k xh[n][k]*Wfo[o][k] + shW[o] ) ) ----
__global__ __launch_bounds__(256) void gemm_kernel(
    const f16* __restrict__ xh, const f16* __restrict__ Wfo,
    const float* __restrict__ shW, const float* __restrict__ dis,
    f16* __restrict__ h, int N, int nrg)
{
    const int lane = threadIdx.x & 63;
    const int l15 = lane & 15;
    const int lh = lane >> 4;

    f16x8 af[8][4];
    #pragma unroll
    for (int t = 0; t < 8; t++)
        #pragma unroll
        for (int kb = 0; kb < 4; kb++)
            af[t][kb] = *reinterpret_cast<const f16x8*>(
                &Wfo[(t * 16 + l15) * D + kb * 32 + lh * 8]);

    const int wid = (blockIdx.x * blockDim.x + threadIdx.x) >> 6;
    const int nwaves = (gridDim.x * blockDim.x) >> 6;

    for (int rg = wid; rg < nrg; rg += nwaves) {
        int row = rg * 16 + l15;
        int rrow = min(row, N - 1);
        f16x8 bf[4];
        #pragma unroll
        for (int kb = 0; kb < 4; kb++)
            bf[kb] = *reinterpret_cast<const f16x8*>(
                &xh[(long long)rrow * D + kb * 32 + lh * 8]);
        float d = dis[rrow];
        bool ok = (row < N);

        #pragma unroll
        for (int t = 0; t < 8; t++) {
            f32x4 acc = {0.0f, 0.0f, 0.0f, 0.0f};
            #pragma unroll
            for (int kb = 0; kb < 4; kb++)
                acc = __builtin_amdgcn_mfma_f32_16x16x32_f16(af[t][kb], bf[kb], acc, 0, 0, 0);
            int o0 = t * 16 + lh * 4;
            float4 sw = *reinterpret_cast<const float4*>(&shW[o0]);
            f16x4 ov;
            ov[0] = (f16)(d * (acc[0] + sw.x));
            ov[1] = (f16)(d * (acc[1] + sw.y));
            ov[2] = (f16)(d * (acc[2] + sw.z));
            ov[3] = (f16)(d * (acc[3] + sw.w));
            if (ok)
                *reinterpret_cast<f16x4*>(&h[(long long)row * D + o0]) = ov;
        }
    }
}

// ---- fused gather + finalize: 16 lanes/node, f16x8 loads, 2-way unroll ----
__global__ __launch_bounds__(256) void gather_kernel(
    const f16* __restrict__ h, const int* __restrict__ offs,
    const int* __restrict__ srcs, const float* __restrict__ dis,
    const float* __restrict__ bias, f16* __restrict__ t,
    float* __restrict__ stats, int N)
{
    const int tid = threadIdx.x;
    const int l16 = tid & 15;
    const int grp = tid >> 4;            // 16 node-groups per block
    const int f8 = l16 * 8;
    float bv[8];
    {
        float4 ba = *reinterpret_cast<const float4*>(&bias[f8]);
        float4 bb = *reinterpret_cast<const float4*>(&bias[f8 + 4]);
        bv[0] = ba.x; bv[1] = ba.y; bv[2] = ba.z; bv[3] = ba.w;
        bv[4] = bb.x; bv[5] = bb.y; bv[6] = bb.z; bv[7] = bb.w;
    }
    float ssum[8] = {0, 0, 0, 0, 0, 0, 0, 0}, ssq[8] = {0, 0, 0, 0, 0, 0, 0, 0};

    for (int c = blockIdx.x * 16 + grp; c < N; c += gridDim.x * 16) {
        f16x8 hv = *reinterpret_cast<const f16x8*>(&h[(long long)c * D + f8]);  // self
        float a[8], a2[8];
        #pragma unroll
        for (int m = 0; m < 8; m++) { a[m] = (float)hv[m]; a2[m] = 0.0f; }
        const int k0 = offs[c], k1 = offs[c + 1];
        for (int kb = k0; kb < k1; kb += 16) {
            int kk = kb + l16;
            int rl = (kk < k1) ? srcs[kk] : 0;
            int cnt = min(16, k1 - kb);
            int j = 0;
            for (; j + 2 <= cnt; j += 2) {
                int r0 = __shfl(rl, j, 16);
                int r1 = __shfl(rl, j + 1, 16);
                f16x8 v0 = *reinterpret_cast<const f16x8*>(&h[(long long)r0 * D + f8]);
                f16x8 v1 = *reinterpret_cast<const f16x8*>(&h[(long long)r1 * D + f8]);
                #pragma unroll
                for (int m = 0; m < 8; m++) { a[m] += (float)v0[m]; a2[m] += (float)v1[m]; }
            }
            if (j < cnt) {
                int r0 = __shfl(rl, j, 16);
                f16x8 v0 = *reinterpret_cast<const f16x8*>(&h[(long long)r0 * D + f8]);
                #pragma unroll
                for (int m = 0; m < 8; m++) a[m] += (float)v0[m];
            }
        }
        float d = dis[c];
        float tv[8];
        float s = 0.0f;
        #pragma unroll
        for (int m = 0; m < 8; m++) {
            tv[m] = d * (a[m] + a2[m]) + bv[m];
            s += tv[m];
        }
        #pragma unroll
        for (int off = 1; off < 16; off <<= 1) s += __shfl_xor(s, off, 16);
        float mean = s * (1.0f / 128.0f);
        f16x8 ov;
        #pragma unroll
        for (int m = 0; m < 8; m++) {
            tv[m] -= mean;
            ov[m] = (f16)tv[m];
            ssum[m] += tv[m];
            ssq[m] += tv[m] * tv[m];
        }
        *reinterpret_cast<f16x8*>(&t[(long long)c * D + f8]) = ov;
    }

    __shared__ float red[256 * 16];
    #pragma unroll
    for (int j = 0; j < 8; j++) {
        red[tid * 16 + j] = ssum[j];
        red[tid * 16 + 8 + j] = ssq[j];
    }
    __syncthreads();
    const int o = tid;
    const int f = o & 127;
    const int sq = o >> 7;
    const int lf = f >> 3;
    const int j = f & 7;
    float v = 0;
    #pragma unroll
    for (int g = 0; g < 16; g++)
        v += red[(g * 16 + lf) * 16 + sq * 8 + j];
    unsafeAtomicAdd(&stats[o], v);
}

// ---- fold BN stats into scale/shift ----
__global__ void stats_kernel(const float* __restrict__ stats,
                             const float* __restrict__ gamma,
                             const float* __restrict__ beta,
                             float* __restrict__ scsh, float Ninv)
{
    int j = threadIdx.x;
    float mu = stats[j] * Ninv;
    float var = stats[D + j] * Ninv - mu * mu;
    float inv = rsqrtf(var + EPSV);
    float sc = gamma[j] * inv;
    scsh[j] = sc;
    scsh[D + j] = beta[j] - mu * sc;
}

// ---- final BN apply: out(f32) = t(fp16)*sc + sh ----
__global__ __launch_bounds__(256) void epi2_kernel(
    const f16* __restrict__ t, const float* __restrict__ scsh,
    float* __restrict__ out, long long total4)
{
    __shared__ float sc[D], sh[D];
    if (threadIdx.x < D) {
        sc[threadIdx.x] = scsh[threadIdx.x];
        sh[threadIdx.x] = scsh[D + threadIdx.x];
    }
    __syncthreads();
    long long i = (long long)blockIdx.x * blockDim.x + threadIdx.x;
    const long long stride = (long long)gridDim.x * blockDim.x;
    for (; i < total4; i += stride) {
        f16x4 v = reinterpret_cast<const f16x4*>(t)[i];
        int f0 = (int)((i * 4) & (D - 1));
        float4 o;
        o.x = (float)v[0] * sc[f0 + 0] + sh[f0 + 0];
        o.y = (float)v[1] * sc[f0 + 1] + sh[f0 + 1];
        o.z = (float)v[2] * sc[f0 + 2] + sh[f0 + 2];
        o.w = (float)v[3] * sc[f0 + 3] + sh[f0 + 3];
        reinterpret_cast<float4*>(out)[i] = o;
    }
}

extern "C" void kernel_launch(void* const* d_in, const int* in_sizes, int n_in,
                              void* d_out, int out_size, void* d_ws, size_t ws_size,
                              hipStream_t stream)
{
    const float* x_in  = (const float*)d_in[0];
    const int*   ei    = (const int*)d_in[1];
    const float* W     = (const float*)d_in[2];
    const float* bias  = (const float*)d_in[3];
    const float* gamma = (const float*)d_in[4];
    const float* beta  = (const float*)d_in[5];

    const int N = in_sizes[0] / D;
    const int E = in_sizes[1] / 2;
    const int L = in_sizes[2] / (D * D);
    const int* row = ei;           // source
    const int* col = ei + E;       // target
    const int NB = (N + 255) / 256;
    const int NBUCK = (N + 255) >> 8;   // 256 cols per bucket
    const int seg = NBUCK * 8;
    const int nrg = (N + 15) / 16;

    // ws layout: [f16: tbuf | hbuf | Wfo] [f32: dis | stats | scsh | shW]
    //            [int: deg | offs | srcs | bsum | gb | soff | cur] [int2: bpairs]
    f16* tbuf = (f16*)d_ws;
    f16* hbuf = tbuf + (size_t)N * D;
    f16* Wfo  = hbuf + (size_t)N * D;
    float* dis   = (float*)(Wfo + D * D);
    float* stats = dis + N;
    float* scsh  = stats + 2 * D;
    float* shW   = scsh + 2 * D;
    int* deg  = (int*)(shW + D);
    int* offs = deg + N;
    int* srcs = offs + (N + 1);
    int* bsum = srcs + E;
    int* gb   = bsum + 512;
    int* soff = gb + 4096;
    int* cur  = soff + 4097;
    size_t cur_end = (size_t)(cur + 4096 * 16 - (int*)d_ws);
    int2* bpairs = (int2*)((int*)d_ws + ((cur_end + 1) & ~(size_t)1));

    // ---- CSR build ----
    hipMemsetAsync(gb, 0, 4096 * sizeof(int), stream);
    bcount_kernel<<<128, 256, 0, stream>>>(col, gb, E, seg);
    bscan_kernel<<<1, 1024, 0, stream>>>(gb, soff, cur);
    bfill_kernel<<<1024, 256, 0, stream>>>(row, col, cur, bpairs, E);
    bdeg_kernel<<<NBUCK, 256, 0, stream>>>(bpairs, soff, deg, dis, N);
    scan1_kernel<<<NB, 256, 0, stream>>>(deg, offs, bsum, N);
    scan2_kernel<<<1, 512, 0, stream>>>(bsum, NB);
    scan3_kernel<<<NB, 256, 0, stream>>>(offs, bsum, N, E);
    cfill_kernel<<<NBUCK, 256, 0, stream>>>(bpairs, soff, offs, srcs, N);

    const float Ninv = 1.0f / (float)N;
    const long long total4 = (long long)N * D / 4;

    cvt_kernel<<<2048, 256, 0, stream>>>(x_in, tbuf, total4);
    fold_kernel<<<D, D, 0, stream>>>(W, scsh, 1, Wfo, shW);   // layer 0: identity fold

    for (int l = 0; l < L; l++) {
        gemm_kernel<<<512, 256, 0, stream>>>(tbuf, Wfo, shW, dis, hbuf, N, nrg);
        hipMemsetAsync(stats, 0, 2 * D * sizeof(float), stream);
        gather_kernel<<<2048, 256, 0, stream>>>(
            hbuf, offs, srcs, dis, bias + (size_t)l * D, tbuf, stats, N);
        stats_kernel<<<1, D, 0, stream>>>(
            stats, gamma + (size_t)l * D, beta + (size_t)l * D, scsh, Ninv);
        if (l < L - 1)
            fold_kernel<<<D, D, 0, stream>>>(W + (size_t)(l + 1) * D * D, scsh, 0, Wfo, shW);
        else
            epi2_kernel<<<4096, 256, 0, stream>>>(tbuf, scsh, (float*)d_out, total4);
    }
}